// Round 2
// baseline (315.167 us; speedup 1.0000x reference)
//
#include <hip/hip_runtime.h>

#define N 8192
#define H 256
#define TOPK 16
#define NSEC 11
#define NEG_SLOPE 0.2

// ---------------------------------------------------------------------------
// Kernel 1: v1 = W^T a1, v2 = W^T a2   (W is HxH row-major, a is 2H)
// One block, 256 threads: thread k owns output column k. For fixed j, the 256
// threads read W[j*H + k] -> fully coalesced 1KB lines.
// ---------------------------------------------------------------------------
__global__ __launch_bounds__(256) void compute_v(const float* __restrict__ W,
                                                 const float* __restrict__ a,
                                                 double* __restrict__ v1,
                                                 double* __restrict__ v2) {
    int k = threadIdx.x;
    double acc1 = 0.0, acc2 = 0.0;
    for (int j = 0; j < H; ++j) {
        double w = (double)W[j * H + k];
        acc1 += w * (double)a[j];
        acc2 += w * (double)a[H + j];
    }
    v1[k] = acc1;
    v2[k] = acc2;
}

// ---------------------------------------------------------------------------
// Kernel 2: s1[i] = E[i,:]·v1, s2[i] = E[i,:]·v2.
// One wave (64 lanes) per row; lane l loads float4 at col 4l. f64 accumulate,
// wave shuffle reduction. Grid = N/4 blocks of 256 threads (4 waves/block).
// ---------------------------------------------------------------------------
__global__ __launch_bounds__(256) void compute_s(const float* __restrict__ E,
                                                 const double* __restrict__ v1,
                                                 const double* __restrict__ v2,
                                                 double* __restrict__ s1,
                                                 double* __restrict__ s2) {
    __shared__ double sv1[H];
    __shared__ double sv2[H];
    int t = threadIdx.x;
    sv1[t] = v1[t];
    sv2[t] = v2[t];
    __syncthreads();

    int wave = t >> 6;
    int lane = t & 63;
    int row = blockIdx.x * 4 + wave;

    const float4* Erow = (const float4*)(E + (size_t)row * H);
    float4 e = Erow[lane];
    int base = lane * 4;
    double acc1 = (double)e.x * sv1[base + 0] + (double)e.y * sv1[base + 1] +
                  (double)e.z * sv1[base + 2] + (double)e.w * sv1[base + 3];
    double acc2 = (double)e.x * sv2[base + 0] + (double)e.y * sv2[base + 1] +
                  (double)e.z * sv2[base + 2] + (double)e.w * sv2[base + 3];

    for (int o = 32; o > 0; o >>= 1) {
        acc1 += __shfl_down(acc1, o);
        acc2 += __shfl_down(acc2, o);
    }
    if (lane == 0) {
        s1[row] = acc1;
        s2[row] = acc2;
    }
}

// ---------------------------------------------------------------------------
// Kernel 3: per-sector top-16 of s2 over {j : active[j] && sec[j]==c}.
// One block per sector. 16 rounds of block-wide argmax with comparator
// (value desc, index asc); round r only considers entries strictly "worse"
// than round r-1's pick, so no mutation/flags needed.
// Also emits filler indices: first 16 j failing the predicate (for m<16).
// ---------------------------------------------------------------------------
__device__ __forceinline__ bool better(double av, int ai, double bv, int bi) {
    return (av > bv) || (av == bv && ai < bi);
}

__global__ __launch_bounds__(256) void topk_sector(const double* __restrict__ s2,
                                                   const int* __restrict__ sec,
                                                   const int* __restrict__ act,
                                                   int* __restrict__ top_idx,
                                                   int* __restrict__ fill_idx,
                                                   int* __restrict__ m_out) {
    __shared__ double red_v[256];
    __shared__ int red_i[256];
    __shared__ double sh_last_v;
    __shared__ int sh_last_i;

    int c = blockIdx.x;
    int t = threadIdx.x;

    double last_v = INFINITY;  // sentinel: everything finite is worse than this
    int last_i = -1;
    int found = 0;

    for (int r = 0; r < TOPK; ++r) {
        double bv = -INFINITY;
        int bi = 0x7fffffff;
        for (int j = t; j < N; j += 256) {
            if (act[j] != 0 && sec[j] == c) {
                double v = s2[j];
                // strictly worse than last pick: (v,j) < (last_v,last_i)
                bool worse = (v < last_v) || (v == last_v && j > last_i);
                if (worse && better(v, j, bv, bi)) {
                    bv = v;
                    bi = j;
                }
            }
        }
        red_v[t] = bv;
        red_i[t] = bi;
        __syncthreads();
        for (int s = 128; s > 0; s >>= 1) {
            if (t < s) {
                if (better(red_v[t + s], red_i[t + s], red_v[t], red_i[t])) {
                    red_v[t] = red_v[t + s];
                    red_i[t] = red_i[t + s];
                }
            }
            __syncthreads();
        }
        if (t == 0) {
            sh_last_v = red_v[0];
            sh_last_i = red_i[0];
            if (red_i[0] != 0x7fffffff) {
                top_idx[c * TOPK + r] = red_i[0];
            } else {
                top_idx[c * TOPK + r] = -1;
            }
        }
        __syncthreads();
        last_v = sh_last_v;
        last_i = sh_last_i;
        if (last_i != 0x7fffffff) ++found;
        __syncthreads();
    }

    if (t == 0) {
        m_out[c] = found;
        int cnt = 0;
        for (int j = 0; j < N && cnt < TOPK; ++j) {
            if (!(act[j] != 0 && sec[j] == c)) fill_idx[c * TOPK + cnt++] = j;
        }
        for (; cnt < TOPK; ++cnt) fill_idx[c * TOPK + cnt] = 0;
    }
}

// ---------------------------------------------------------------------------
// Kernel 4: write outputs. 16 consecutive threads per row -> coalesced writes
// to all three planes (edge_weight, indices-as-float, valid-as-float).
// ---------------------------------------------------------------------------
__global__ __launch_bounds__(256) void write_out(const double* __restrict__ s1,
                                                 const double* __restrict__ s2,
                                                 const int* __restrict__ sec,
                                                 const int* __restrict__ act,
                                                 const int* __restrict__ top_idx,
                                                 const int* __restrict__ fill_idx,
                                                 const int* __restrict__ m_arr,
                                                 float* __restrict__ out) {
    int gid = blockIdx.x * 256 + threadIdx.x;  // N*TOPK total
    int i = gid >> 4;
    int slot = gid & 15;

    float w = 0.0f;
    float fidx;
    float fvalid = 0.0f;

    if (act[i] == 0) {
        fidx = (float)slot;  // all -inf row: stable top_k -> indices 0..15
    } else {
        int c = sec[i];
        int m = m_arr[c];
        if (slot < m) {
            int j = top_idx[c * TOPK + slot];
            double x = s1[i] + s2[j];
            double attv = (x >= 0.0) ? x : NEG_SLOPE * x;
            w = (float)attv;
            fvalid = 1.0f;
            fidx = (float)j;
        } else {
            fidx = (float)fill_idx[c * TOPK + (slot - m)];
        }
    }

    out[gid] = w;
    out[N * TOPK + gid] = fidx;
    out[2 * N * TOPK + gid] = fvalid;
}

extern "C" void kernel_launch(void* const* d_in, const int* in_sizes, int n_in,
                              void* d_out, int out_size, void* d_ws, size_t ws_size,
                              hipStream_t stream) {
    const float* E = (const float*)d_in[0];
    const float* W = (const float*)d_in[1];
    const float* a = (const float*)d_in[2];
    const int* sec = (const int*)d_in[3];
    const int* act = (const int*)d_in[4];   // bool input uploaded as int32

    char* ws = (char*)d_ws;
    double* v1 = (double*)ws;        // 256 doubles
    double* v2 = v1 + H;             // 256 doubles
    double* s1 = v2 + H;             // N doubles
    double* s2 = s1 + N;             // N doubles
    int* top_idx = (int*)(s2 + N);   // NSEC*TOPK ints
    int* fill_idx = top_idx + NSEC * TOPK;
    int* m_arr = fill_idx + NSEC * TOPK;

    float* out = (float*)d_out;

    hipLaunchKernelGGL(compute_v, dim3(1), dim3(256), 0, stream, W, a, v1, v2);
    hipLaunchKernelGGL(compute_s, dim3(N / 4), dim3(256), 0, stream, E, v1, v2, s1, s2);
    hipLaunchKernelGGL(topk_sector, dim3(NSEC), dim3(256), 0, stream, s2, sec, act,
                       top_idx, fill_idx, m_arr);
    hipLaunchKernelGGL(write_out, dim3((N * TOPK) / 256), dim3(256), 0, stream,
                       s1, s2, sec, act, top_idx, fill_idx, m_arr, out);
}

// Round 3
// 150.857 us; speedup vs baseline: 2.0892x; 2.0892x over previous
//
#include <hip/hip_runtime.h>

#define N 8192
#define H 256
#define TOPK 16
#define NSEC 11
#define NEG_SLOPE 0.2
#define CAP 1024  // per-sector compaction capacity (expected ~372, 30+ sigma margin)

__device__ __forceinline__ bool better(double av, int ai, double bv, int bi) {
    return (av > bv) || (av == bv && ai < bi);
}

// ---------------------------------------------------------------------------
// Kernel 1: v1 = W^T a1, v2 = W^T a2. 1024 threads: k = t&255 owns column,
// g = t>>8 covers a 64-row j-slice; LDS reduce 4 partials. Coalesced W reads.
// ---------------------------------------------------------------------------
__global__ __launch_bounds__(1024) void compute_v(const float* __restrict__ W,
                                                  const float* __restrict__ a,
                                                  double* __restrict__ v1,
                                                  double* __restrict__ v2) {
    __shared__ double part1[4][256];
    __shared__ double part2[4][256];
    int k = threadIdx.x & 255;
    int g = threadIdx.x >> 8;
    double acc1 = 0.0, acc2 = 0.0;
    for (int j = g * 64; j < (g + 1) * 64; ++j) {
        double w = (double)W[j * H + k];
        acc1 += w * (double)a[j];
        acc2 += w * (double)a[H + j];
    }
    part1[g][k] = acc1;
    part2[g][k] = acc2;
    __syncthreads();
    if (g == 0) {
        v1[k] = part1[0][k] + part1[1][k] + part1[2][k] + part1[3][k];
        v2[k] = part2[0][k] + part2[1][k] + part2[2][k] + part2[3][k];
    }
}

// ---------------------------------------------------------------------------
// Kernel 2: s1[i] = E[i,:]·v1, s2[i] = E[i,:]·v2. One wave per row, float4
// loads, f64 accumulate, shuffle reduce. Grid = N/4 blocks of 256.
// ---------------------------------------------------------------------------
__global__ __launch_bounds__(256) void compute_s(const float* __restrict__ E,
                                                 const double* __restrict__ v1,
                                                 const double* __restrict__ v2,
                                                 double* __restrict__ s1,
                                                 double* __restrict__ s2) {
    __shared__ double sv1[H];
    __shared__ double sv2[H];
    int t = threadIdx.x;
    sv1[t] = v1[t];
    sv2[t] = v2[t];
    __syncthreads();

    int wave = t >> 6;
    int lane = t & 63;
    int row = blockIdx.x * 4 + wave;

    const float4* Erow = (const float4*)(E + (size_t)row * H);
    float4 e = Erow[lane];
    int base = lane * 4;
    double acc1 = (double)e.x * sv1[base + 0] + (double)e.y * sv1[base + 1] +
                  (double)e.z * sv1[base + 2] + (double)e.w * sv1[base + 3];
    double acc2 = (double)e.x * sv2[base + 0] + (double)e.y * sv2[base + 1] +
                  (double)e.z * sv2[base + 2] + (double)e.w * sv2[base + 3];

    for (int o = 32; o > 0; o >>= 1) {
        acc1 += __shfl_down(acc1, o);
        acc2 += __shfl_down(acc2, o);
    }
    if (lane == 0) {
        s1[row] = acc1;
        s2[row] = acc2;
    }
}

// ---------------------------------------------------------------------------
// Kernel 3: per-sector top-16. Single pass: wave-ballot compaction of active
// sector members into LDS (<= CAP), bitonic sort (desc by (val, -idx)), take
// first 16. Fallback to 16-round argmax if CAP overflows (never for this
// input, but keeps correctness unconditional). Fill indices via wave ballot.
// ---------------------------------------------------------------------------
__global__ __launch_bounds__(256) void topk_sector(const double* __restrict__ s2,
                                                   const int* __restrict__ sec,
                                                   const int* __restrict__ act,
                                                   int* __restrict__ top_idx,
                                                   int* __restrict__ fill_idx,
                                                   int* __restrict__ m_out) {
    __shared__ double kv[CAP];
    __shared__ int ki[CAP];
    __shared__ int cnt;

    int c = blockIdx.x;
    int t = threadIdx.x;
    int lane = t & 63;

    if (t == 0) cnt = 0;
    __syncthreads();

    // --- compaction: one coalesced pass over N ---
    for (int j = t; j < N; j += 256) {
        bool pred = (act[j] != 0) && (sec[j] == c);
        unsigned long long mask = __ballot(pred);
        int nact = __popcll(mask);
        if (nact > 0) {
            int leader = (int)__ffsll((unsigned long long)mask) - 1;
            int b = 0;
            if (lane == leader) b = atomicAdd(&cnt, nact);
            b = __shfl(b, leader);
            if (pred) {
                int pos = b + __popcll(mask & ((1ull << lane) - 1));
                if (pos < CAP) {
                    kv[pos] = s2[j];
                    ki[pos] = j;
                }
            }
        }
    }
    __syncthreads();
    int total = cnt;

    if (total <= CAP) {
        // pad to CAP with worst sentinel
        for (int p = total + t; p < CAP; p += 256) {
            kv[p] = -INFINITY;
            ki[p] = 0x7fffffff;
        }
        __syncthreads();
        // bitonic sort, final order descending by better()
        for (int k = 2; k <= CAP; k <<= 1) {
            for (int j = k >> 1; j > 0; j >>= 1) {
                for (int idx = t; idx < CAP; idx += 256) {
                    int ixj = idx ^ j;
                    if (ixj > idx) {
                        bool desc = ((idx & k) == 0);
                        double v0 = kv[idx], vx = kv[ixj];
                        int i0 = ki[idx], ix = ki[ixj];
                        bool sw = desc ? better(vx, ix, v0, i0) : better(v0, i0, vx, ix);
                        if (sw) {
                            kv[idx] = vx; ki[idx] = ix;
                            kv[ixj] = v0; ki[ixj] = i0;
                        }
                    }
                }
                __syncthreads();
            }
        }
        if (t < TOPK) top_idx[c * TOPK + t] = (t < total) ? ki[t] : -1;
        if (t == 0) m_out[c] = (total < TOPK) ? total : TOPK;
    } else {
        // --- fallback: original 16-round argmax over global (correct for any count) ---
        __shared__ double red_v[256];
        __shared__ int red_i[256];
        __shared__ double sh_last_v;
        __shared__ int sh_last_i;
        double last_v = INFINITY;
        int last_i = -1;
        int found = 0;
        for (int r = 0; r < TOPK; ++r) {
            double bv = -INFINITY;
            int bi = 0x7fffffff;
            for (int j = t; j < N; j += 256) {
                if (act[j] != 0 && sec[j] == c) {
                    double v = s2[j];
                    bool worse = (v < last_v) || (v == last_v && j > last_i);
                    if (worse && better(v, j, bv, bi)) { bv = v; bi = j; }
                }
            }
            red_v[t] = bv;
            red_i[t] = bi;
            __syncthreads();
            for (int s = 128; s > 0; s >>= 1) {
                if (t < s) {
                    if (better(red_v[t + s], red_i[t + s], red_v[t], red_i[t])) {
                        red_v[t] = red_v[t + s];
                        red_i[t] = red_i[t + s];
                    }
                }
                __syncthreads();
            }
            if (t == 0) {
                sh_last_v = red_v[0];
                sh_last_i = red_i[0];
                top_idx[c * TOPK + r] = (red_i[0] != 0x7fffffff) ? red_i[0] : -1;
            }
            __syncthreads();
            last_v = sh_last_v;
            last_i = sh_last_i;
            if (last_i != 0x7fffffff) ++found;
            __syncthreads();
        }
        if (t == 0) m_out[c] = found;
    }

    // --- fill indices: first 16 j failing the predicate, wave-cooperative ---
    if (t < 64) {
        int cnt2 = 0;
        for (int base = 0; base < N && cnt2 < TOPK; base += 64) {
            int j = base + lane;
            bool fail = !((act[j] != 0) && (sec[j] == c));
            unsigned long long mask = __ballot(fail);
            if (fail) {
                int rank = cnt2 + __popcll(mask & ((1ull << lane) - 1));
                if (rank < TOPK) fill_idx[c * TOPK + rank] = j;
            }
            cnt2 += __popcll(mask);
        }
    }
}

// ---------------------------------------------------------------------------
// Kernel 4: write outputs (weight, index-as-float, valid-as-float planes).
// ---------------------------------------------------------------------------
__global__ __launch_bounds__(256) void write_out(const double* __restrict__ s1,
                                                 const double* __restrict__ s2,
                                                 const int* __restrict__ sec,
                                                 const int* __restrict__ act,
                                                 const int* __restrict__ top_idx,
                                                 const int* __restrict__ fill_idx,
                                                 const int* __restrict__ m_arr,
                                                 float* __restrict__ out) {
    int gid = blockIdx.x * 256 + threadIdx.x;  // N*TOPK total
    int i = gid >> 4;
    int slot = gid & 15;

    float w = 0.0f;
    float fidx;
    float fvalid = 0.0f;

    if (act[i] == 0) {
        fidx = (float)slot;  // all -inf row: stable top_k -> indices 0..15
    } else {
        int c = sec[i];
        int m = m_arr[c];
        if (slot < m) {
            int j = top_idx[c * TOPK + slot];
            double x = s1[i] + s2[j];
            double attv = (x >= 0.0) ? x : NEG_SLOPE * x;
            w = (float)attv;
            fvalid = 1.0f;
            fidx = (float)j;
        } else {
            fidx = (float)fill_idx[c * TOPK + (slot - m)];
        }
    }

    out[gid] = w;
    out[N * TOPK + gid] = fidx;
    out[2 * N * TOPK + gid] = fvalid;
}

extern "C" void kernel_launch(void* const* d_in, const int* in_sizes, int n_in,
                              void* d_out, int out_size, void* d_ws, size_t ws_size,
                              hipStream_t stream) {
    const float* E = (const float*)d_in[0];
    const float* W = (const float*)d_in[1];
    const float* a = (const float*)d_in[2];
    const int* sec = (const int*)d_in[3];
    const int* act = (const int*)d_in[4];  // bool input uploaded as int32

    char* ws = (char*)d_ws;
    double* v1 = (double*)ws;         // 256
    double* v2 = v1 + H;              // 256
    double* s1 = v2 + H;              // N
    double* s2 = s1 + N;              // N
    int* top_idx = (int*)(s2 + N);    // NSEC*TOPK
    int* fill_idx = top_idx + NSEC * TOPK;
    int* m_arr = fill_idx + NSEC * TOPK;

    float* out = (float*)d_out;

    hipLaunchKernelGGL(compute_v, dim3(1), dim3(1024), 0, stream, W, a, v1, v2);
    hipLaunchKernelGGL(compute_s, dim3(N / 4), dim3(256), 0, stream, E, v1, v2, s1, s2);
    hipLaunchKernelGGL(topk_sector, dim3(NSEC), dim3(256), 0, stream, s2, sec, act,
                       top_idx, fill_idx, m_arr);
    hipLaunchKernelGGL(write_out, dim3((N * TOPK) / 256), dim3(256), 0, stream,
                       s1, s2, sec, act, top_idx, fill_idx, m_arr, out);
}

// Round 6
// 117.362 us; speedup vs baseline: 2.6854x; 1.2854x over previous
//
#include <hip/hip_runtime.h>

#define N 8192
#define H 256
#define TOPK 16
#define NSEC 11
#define NEG_SLOPE 0.2
#define NBLK 32                   // slices in K1
#define RPB (N / NBLK)            // rows per block = 256
#define IDX_SENT 0x7fffffff

__device__ __forceinline__ bool better(double av, int ai, double bv, int bi) {
    return (av > bv) || (av == bv && ai < bi);
}

// ---------------------------------------------------------------------------
// K1: per block: redundant v = W^T a (L2-served), s1/s2 for this block's 256
// rows (identical per-row numerics to round-3-proven kernel; stored f32 —
// only feeds weight values, loose threshold), per-sector slice top-16 kept
// entirely in registers + shuffles (ordering in f64). No atomics, no fences.
// ---------------------------------------------------------------------------
__global__ __launch_bounds__(1024) void fused_v_s(
    const float* __restrict__ E, const float* __restrict__ W,
    const float* __restrict__ a, const int* __restrict__ sec,
    const int* __restrict__ act,
    float* __restrict__ s1f, float* __restrict__ s2f,
    double* __restrict__ candV, int* __restrict__ candI,
    int* __restrict__ cnts)
{
    __shared__ double part1[4][256];
    __shared__ double part2[4][256];
    __shared__ double sv1[H];
    __shared__ double sv2[H];
    __shared__ double s2loc[RPB];

    int t = threadIdx.x;
    int blk = blockIdx.x;
    int lane = t & 63;
    int w = t >> 6;  // wave id 0..15

    // ---- stage A: v1 = W^T a1, v2 = W^T a2 (same summation order as R3) ----
    {
        int k = t & 255;
        int g = t >> 8;
        double acc1 = 0.0, acc2 = 0.0;
        for (int j = g * 64; j < (g + 1) * 64; ++j) {
            double wv = (double)W[j * H + k];
            acc1 += wv * (double)a[j];
            acc2 += wv * (double)a[H + j];
        }
        part1[g][k] = acc1;
        part2[g][k] = acc2;
    }
    __syncthreads();
    if (t < 256) {
        sv1[t] = part1[0][t] + part1[1][t] + part1[2][t] + part1[3][t];
        sv2[t] = part2[0][t] + part2[1][t] + part2[2][t] + part2[3][t];
    }
    __syncthreads();

    // ---- stage B: s1,s2 for rows [blk*256, blk*256+256), wave-per-row ----
    for (int q = 0; q < RPB / 16; ++q) {
        int r_loc = w + 16 * q;
        int row = blk * RPB + r_loc;
        const float4* Erow = (const float4*)(E + (size_t)row * H);
        float4 e = Erow[lane];
        int base = lane * 4;
        double acc1 = (double)e.x * sv1[base + 0] + (double)e.y * sv1[base + 1] +
                      (double)e.z * sv1[base + 2] + (double)e.w * sv1[base + 3];
        double acc2 = (double)e.x * sv2[base + 0] + (double)e.y * sv2[base + 1] +
                      (double)e.z * sv2[base + 2] + (double)e.w * sv2[base + 3];
        for (int o = 32; o > 0; o >>= 1) {
            acc1 += __shfl_down(acc1, o);
            acc2 += __shfl_down(acc2, o);
        }
        if (lane == 0) {
            s1f[row] = (float)acc1;
            s2f[row] = (float)acc2;
            s2loc[r_loc] = acc2;
        }
    }
    __syncthreads();

    // ---- stage C: per-sector slice top-16 (wave w handles sector w) ----
    if (w < NSEC) {
        int c = w;
        double cv[4];
        int ci[4];
        int count = 0;
        for (int p = 0; p < 4; ++p) {
            int r_loc = p * 64 + lane;
            int j = blk * RPB + r_loc;
            bool pred = (act[j] != 0) && (sec[j] == c);
            cv[p] = pred ? s2loc[r_loc] : -INFINITY;
            ci[p] = pred ? j : IDX_SENT;
            count += __popcll(__ballot(pred));
        }

        for (int r = 0; r < TOPK; ++r) {
            double bv = cv[0];
            int bi = ci[0];
            for (int p = 1; p < 4; ++p)
                if (better(cv[p], ci[p], bv, bi)) { bv = cv[p]; bi = ci[p]; }
            for (int o = 32; o > 0; o >>= 1) {
                double ov = __shfl_xor(bv, o);
                int oi = __shfl_xor(bi, o);
                if (better(ov, oi, bv, bi)) { bv = ov; bi = oi; }
            }
            if (bi != IDX_SENT) {
                for (int p = 0; p < 4; ++p)
                    if (ci[p] == bi) { cv[p] = -INFINITY; ci[p] = IDX_SENT; }
            }
            if (lane == 0) {
                candV[(c * NBLK + blk) * TOPK + r] = bv;
                candI[(c * NBLK + blk) * TOPK + r] = bi;
            }
        }
        if (lane == 0) cnts[c * NBLK + blk] = count;
    }
}

// ---------------------------------------------------------------------------
// K2: one wave per sector (blockIdx = sector). Merge NBLK sorted 16-lists by
// repeated wave-argmax over per-lane heads; also m and fill indices.
// Cross-kernel visibility of candV/candI is guaranteed by stream ordering.
// ---------------------------------------------------------------------------
__global__ __launch_bounds__(64) void merge_topk(
    const double* __restrict__ candV, const int* __restrict__ candI,
    const int* __restrict__ cnts, const int* __restrict__ sec,
    const int* __restrict__ act,
    int* __restrict__ top_idx, int* __restrict__ fill_idx,
    int* __restrict__ m_out)
{
    int c = blockIdx.x;
    int lane = threadIdx.x;
    bool has = (lane < NBLK);

    const double* mybV = candV + (size_t)(c * NBLK + (has ? lane : 0)) * TOPK;
    const int* mybI = candI + (size_t)(c * NBLK + (has ? lane : 0)) * TOPK;

    double v0 = has ? mybV[0] : -INFINITY;
    int i0 = has ? mybI[0] : IDX_SENT;
    double v1 = has ? mybV[1] : -INFINITY;
    int i1 = has ? mybI[1] : IDX_SENT;
    int h = 0;  // position of (v0,i0) within this lane's list

    for (int r = 0; r < TOPK; ++r) {
        double bv = v0;
        int bi = i0;
        for (int o = 32; o > 0; o >>= 1) {
            double ov = __shfl_xor(bv, o);
            int oi = __shfl_xor(bi, o);
            if (better(ov, oi, bv, bi)) { bv = ov; bi = oi; }
        }
        bool win = has && (i0 == bi) && (v0 == bv || (i0 == IDX_SENT));
        if (win) {
            ++h;
            v0 = v1;
            i0 = i1;
            if (h + 1 < TOPK) {
                v1 = mybV[h + 1];
                i1 = mybI[h + 1];
            } else {
                v1 = -INFINITY;
                i1 = IDX_SENT;
            }
        }
        if (lane == 0) top_idx[c * TOPK + r] = (bi == IDX_SENT) ? -1 : bi;
    }

    // m = min(16, total active in sector)
    int cl = has ? cnts[c * NBLK + lane] : 0;
    for (int o = 32; o > 0; o >>= 1) cl += __shfl_xor(cl, o);
    if (lane == 0) m_out[c] = (cl < TOPK) ? cl : TOPK;

    // fill indices: first 16 j failing the predicate (wave ballot scan)
    int cnt2 = 0;
    for (int basej = 0; basej < N && cnt2 < TOPK; basej += 64) {
        int j = basej + lane;
        bool fail = !((act[j] != 0) && (sec[j] == c));
        unsigned long long mask = __ballot(fail);
        if (fail) {
            int rank = cnt2 + __popcll(mask & ((1ull << lane) - 1));
            if (rank < TOPK) fill_idx[c * TOPK + rank] = j;
        }
        cnt2 += __popcll(mask);
    }
}

// ---------------------------------------------------------------------------
// K3: write outputs (weight, index-as-float, valid-as-float planes).
// ---------------------------------------------------------------------------
__global__ __launch_bounds__(256) void write_out(const float* __restrict__ s1f,
                                                 const float* __restrict__ s2f,
                                                 const int* __restrict__ sec,
                                                 const int* __restrict__ act,
                                                 const int* __restrict__ top_idx,
                                                 const int* __restrict__ fill_idx,
                                                 const int* __restrict__ m_arr,
                                                 float* __restrict__ out) {
    int gid = blockIdx.x * 256 + threadIdx.x;  // N*TOPK total
    int i = gid >> 4;
    int slot = gid & 15;

    float wgt = 0.0f;
    float fidx;
    float fvalid = 0.0f;

    if (act[i] == 0) {
        fidx = (float)slot;  // all -inf row: stable top_k -> indices 0..15
    } else {
        int c = sec[i];
        int m = m_arr[c];
        if (slot < m) {
            int j = top_idx[c * TOPK + slot];
            double x = (double)s1f[i] + (double)s2f[j];
            double attv = (x >= 0.0) ? x : NEG_SLOPE * x;
            wgt = (float)attv;
            fvalid = 1.0f;
            fidx = (float)j;
        } else {
            fidx = (float)fill_idx[c * TOPK + (slot - m)];
        }
    }

    out[gid] = wgt;
    out[N * TOPK + gid] = fidx;
    out[2 * N * TOPK + gid] = fvalid;
}

extern "C" void kernel_launch(void* const* d_in, const int* in_sizes, int n_in,
                              void* d_out, int out_size, void* d_ws, size_t ws_size,
                              hipStream_t stream) {
    const float* E = (const float*)d_in[0];
    const float* W = (const float*)d_in[1];
    const float* a = (const float*)d_in[2];
    const int* sec = (const int*)d_in[3];
    const int* act = (const int*)d_in[4];  // bool input uploaded as int32

    // workspace layout (8-byte aligned first): total ~135 KB
    char* ws = (char*)d_ws;
    double* candV = (double*)ws;                       // NSEC*NBLK*TOPK = 5632 f64
    float* s1f = (float*)(candV + NSEC * NBLK * TOPK); // N f32
    float* s2f = s1f + N;                              // N f32
    int* candI = (int*)(s2f + N);                      // 5632 i32
    int* cnts = candI + NSEC * NBLK * TOPK;            // NSEC*NBLK = 352
    int* top_idx = cnts + NSEC * NBLK;                 // NSEC*TOPK
    int* fill_idx = top_idx + NSEC * TOPK;             // NSEC*TOPK
    int* m_arr = fill_idx + NSEC * TOPK;               // NSEC

    float* out = (float*)d_out;

    hipLaunchKernelGGL(fused_v_s, dim3(NBLK), dim3(1024), 0, stream,
                       E, W, a, sec, act, s1f, s2f, candV, candI, cnts);
    hipLaunchKernelGGL(merge_topk, dim3(NSEC), dim3(64), 0, stream,
                       candV, candI, cnts, sec, act, top_idx, fill_idx, m_arr);
    hipLaunchKernelGGL(write_out, dim3((N * TOPK) / 256), dim3(256), 0, stream,
                       s1f, s2f, sec, act, top_idx, fill_idx, m_arr, out);
}